// Round 1
// baseline (296.204 us; speedup 1.0000x reference)
//
#include <hip/hip_runtime.h>
#include <hip/hip_bf16.h>
#include <stdint.h>
#include <math.h>

typedef __bf16 bf16;
typedef bf16 bf16x8 __attribute__((ext_vector_type(8)));
typedef bf16 bf16x4 __attribute__((ext_vector_type(4)));
typedef float f32x4 __attribute__((ext_vector_type(4)));
typedef unsigned int u32;

#define TOKENS 8192
#define HD 512
#define NE 8
#define IM 1024
#define ISH 2048
#define CAP 2560   // per-expert slot capacity; mean load 2048, sigma~42

__device__ __forceinline__ void gld16(const void* g, void* l) {
  __builtin_amdgcn_global_load_lds(
      (const __attribute__((address_space(1))) u32*)g,
      (__attribute__((address_space(3))) u32*)l, 16, 0, 0);
}

// ---------------- fused router + weight-convert (one dispatch) ----------------
#define RT_BLOCKS (TOKENS / 4)
#define CVT_BLOCKS 3840
#define CVT_STRIDE (CVT_BLOCKS * 256)   // F4_TOT = 4 * CVT_STRIDE exactly
#define F4_E  (NE * IM * HD / 4)
#define F4_S  (ISH * HD / 4)
#define F4_C1 (F4_E)
#define F4_C2 (F4_C1 + F4_E)
#define F4_C3 (F4_C2 + F4_S)
#define F4_C4 (F4_C3 + F4_S)
#define F4_C5 (F4_C4 + F4_E)
#define F4_TOT (F4_C5 + F4_S)

__launch_bounds__(256)
__global__ void router_cvt_k(const float* __restrict__ x, const float* __restrict__ gw,
                             const float* __restrict__ sgw, float* __restrict__ logits,
                             float* __restrict__ sgate, int* __restrict__ topi,
                             float* __restrict__ topw, int* __restrict__ counts,
                             bf16* __restrict__ xb,
                             const float* __restrict__ e1, const float* __restrict__ e3,
                             const float* __restrict__ s1, const float* __restrict__ s3,
                             const float* __restrict__ e2, const float* __restrict__ s2,
                             bf16* __restrict__ wdst) {
  if (blockIdx.x >= RT_BLOCKS) {
    int idx = (blockIdx.x - RT_BLOCKS) * 256 + threadIdx.x;
#pragma unroll
    for (int it = 0; it < 4; it++, idx += CVT_STRIDE) {
      const float* s; int off;
      if (idx < F4_C1)      { s = e1; off = idx; }
      else if (idx < F4_C2) { s = e3; off = idx - F4_C1; }
      else if (idx < F4_C3) { s = s1; off = idx - F4_C2; }
      else if (idx < F4_C4) { s = s3; off = idx - F4_C3; }
      else if (idx < F4_C5) { s = e2; off = idx - F4_C4; }
      else                  { s = s2; off = idx - F4_C5; }
      const float4 v = ((const float4*)s)[off];
      bf16x4 o;
      o.x = (bf16)v.x; o.y = (bf16)v.y; o.z = (bf16)v.z; o.w = (bf16)v.w;
      ((bf16x4*)wdst)[idx] = o;
    }
    return;
  }
  if (blockIdx.x == 0 && threadIdx.x < NE) counts[threadIdx.x] = 0;
  // gate weights bank-permuted: col c -> (c&7)*64 + c>>3, so gws[e][j*64+lane]
  // is the weight for column lane*8+j (x loaded contiguous-per-lane)
  __shared__ float gws[9][512];
  for (int i = threadIdx.x; i < 9 * 512; i += 256) {
    int r = i >> 9, c = i & 511;
    float v = (r < 8) ? gw[i] : sgw[c];
    gws[r][((c & 7) << 6) | (c >> 3)] = v;
  }
  __syncthreads();
  int wave = threadIdx.x >> 6, lane = threadIdx.x & 63;
  int t = blockIdx.x * 4 + wave;
  const float* xp = x + (size_t)t * HD + lane * 8;
  float4 va = *(const float4*)xp;
  float4 vb = *(const float4*)(xp + 4);
  float xv[8] = {va.x, va.y, va.z, va.w, vb.x, vb.y, vb.z, vb.w};
  {
    bf16x8 xo;
#pragma unroll
    for (int j = 0; j < 8; j++) xo[j] = (bf16)xv[j];
    *(bf16x8*)(xb + (size_t)t * HD + lane * 8) = xo;
  }
  float acc[9];
#pragma unroll
  for (int e = 0; e < 9; e++) {
    float a = 0.f;
#pragma unroll
    for (int j = 0; j < 8; j++) a = fmaf(xv[j], gws[e][j * 64 + lane], a);
    acc[e] = a;
  }
#pragma unroll
  for (int off = 32; off > 0; off >>= 1) {
#pragma unroll
    for (int e = 0; e < 9; e++) acc[e] += __shfl_down(acc[e], off);
  }
  if (lane == 0) {
    float mx = acc[0];
#pragma unroll
    for (int e = 1; e < 8; e++) mx = fmaxf(mx, acc[e]);
    float p[8], sum = 0.f;
#pragma unroll
    for (int e = 0; e < 8; e++) { p[e] = expf(acc[e] - mx); sum += p[e]; }
    float inv = 1.f / sum;
    int i0 = 0; float b0 = p[0];
#pragma unroll
    for (int e = 1; e < 8; e++) if (p[e] > b0) { b0 = p[e]; i0 = e; }
    int i1 = -1; float b1 = -1.f;
#pragma unroll
    for (int e = 0; e < 8; e++) if (e != i0 && p[e] > b1) { b1 = p[e]; i1 = e; }
#pragma unroll
    for (int e = 0; e < 8; e++) logits[(size_t)t * 8 + e] = acc[e];
    topi[2 * t] = i0; topi[2 * t + 1] = i1;
    topw[2 * t] = b0 * inv; topw[2 * t + 1] = b1 * inv;
    sgate[t] = 1.f / (1.f + expf(-acc[8]));
  }
}

// ---------------- dispatch ----------------
__launch_bounds__(256)
__global__ void dispatch_k(const int* __restrict__ topi, const float* __restrict__ topw,
                           int* __restrict__ counts, int* __restrict__ tok,
                           float* __restrict__ wl, int* __restrict__ pos) {
  __shared__ int lcnt[NE];
  __shared__ int lbase[NE];
  int tid = threadIdx.x;
  if (tid < NE) lcnt[tid] = 0;
  __syncthreads();
  int t = blockIdx.x * 256 + tid;
  int e0 = topi[2 * t], e1 = topi[2 * t + 1];
  float w0 = topw[2 * t], w1 = topw[2 * t + 1];
  int r0 = atomicAdd(&lcnt[e0], 1);
  int r1 = atomicAdd(&lcnt[e1], 1);
  __syncthreads();
  if (tid < NE) lbase[tid] = atomicAdd(&counts[tid], lcnt[tid]);
  __syncthreads();
  int p0 = lbase[e0] + r0;
  int p1 = lbase[e1] + r1;
  if (p0 < CAP) { tok[e0 * CAP + p0] = t; wl[e0 * CAP + p0] = w0; }
  if (p1 < CAP) { tok[e1 * CAP + p1] = t; wl[e1 * CAP + p1] = w1; }
  pos[2 * t]     = (p0 < CAP) ? e0 * CAP + p0 : -1;
  pos[2 * t + 1] = (p1 < CAP) ? e1 * CAP + p1 : -1;
}

// ---------------- fused GEMM1: 8-phase 256-class schedule (T2+T3+T4+T5) -------
// BM=256 rows x 128 real-N, dual B (W1 stacked over W3 = 256-row B tile), BK=64,
// 512 threads = 8 waves (2M x 4N), LDS 128KB (2 dbuf x (A 32KB + B 32KB)),
// 1 block/CU. Counted vmcnt(6) at phases 4/8 (vmcnt(0) drain only in the last
// iteration); st_16x32 XOR swizzle (linear gld_lds dest + pre-swizzled global
// source + swizzled ds_read, rule #21); s_setprio around each 16-MFMA cluster.
// Stage schedule (region <- K-tile), derived & paper-verified race-free:
//   ph1: B0d1<-2it+1 | ph2: AQ0d0<-2it+2 | ph3: B1d0 | ph4: AQ1d0 |
//   ph5: B0d0<-2it+2 | ph6: AQ0d1<-2it+3 | ph7: B1d1 | ph8: AQ1d1
// AQ0 = LDS rows 0-63 & 128-191 (both waves' i=0..3), AQ1 = the complement,
// B0 = W1 half (stacked rows 0-127), B1 = W3 half (128-255).
#define LDSA(D) ((D) * 65536)
#define LDSB(D) ((D) * 65536 + 32768)

__launch_bounds__(512, 2)
__global__ void gemm1_k(const bf16* __restrict__ X, const int* __restrict__ tokl,
                        const int* __restrict__ counts,
                        const bf16* __restrict__ e1w, const bf16* __restrict__ e3w,
                        const bf16* __restrict__ s1w, const bf16* __restrict__ s3w,
                        bf16* __restrict__ hmoe, bf16* __restrict__ hsh) {
  const bf16 *W1, *W3;
  bf16* Hout;
  const int* tl = nullptr;
  int cnt = 0, m0, n0, N;
  bool gather;
  int y = blockIdx.y;
  if (y < 80) {
    int e = y / 10, mt = y % 10;
    cnt = min(counts[e], CAP);
    if (mt * 256 >= cnt) return;
    gather = true;
    tl = tokl + e * CAP;
    W1 = e1w + (size_t)e * IM * HD;
    W3 = e3w + (size_t)e * IM * HD;
    Hout = hmoe + (size_t)e * CAP * IM;
    N = IM; m0 = mt * 256; n0 = blockIdx.x * 128;
  } else {
    int s = y - 80;
    gather = false;
    W1 = s1w; W3 = s3w; Hout = hsh; N = ISH;
    m0 = (s >> 1) * 256;
    n0 = ((s & 1) * 8 + blockIdx.x) * 128;
  }

  __shared__ __align__(16) char smem[131072];
  char* lds = (char*)smem;

  int tid = threadIdx.x;
  int lane = tid & 63, wid = tid >> 6;
  int wr = wid >> 2, wc = wid & 3;
  int lrow = lane & 15, lq = lane >> 4;
  // read-side swizzled column byte (within 128B K-tile row)
  int rs = (lq * 16) ^ ((lane & 4) << 3);
  int aoff = wr * 16384 + lrow * 128 + rs;          // + i*2048 + ks*64
  int boff = 32768 + wc * 4096 + lrow * 128 + rs;   // + j*2048 + ks*64 (+16384 for b3)
  // stage-side: thread covers chunk-row rg, swizzled source column colb
  int rg = tid >> 3;
  int colb = ((tid & 7) << 4) ^ (tid & 32);

  const char *gA0, *gA1, *gA2, *gA3;
  if (gather) {
    gA0 = (const char*)(X + (size_t)tl[min(m0 + rg,       cnt - 1)] * HD) + colb;
    gA1 = (const char*)(X + (size_t)tl[min(m0 + 64 + rg,  cnt - 1)] * HD) + colb;
    gA2 = (const char*)(X + (size_t)tl[min(m0 + 128 + rg, cnt - 1)] * HD) + colb;
    gA3 = (const char*)(X + (size_t)tl[min(m0 + 192 + rg, cnt - 1)] * HD) + colb;
  } else {
    gA0 = (const char*)(X + (size_t)(m0 + rg) * HD) + colb;
    gA1 = (const char*)(X + (size_t)(m0 + 64 + rg) * HD) + colb;
    gA2 = (const char*)(X + (size_t)(m0 + 128 + rg) * HD) + colb;
    gA3 = (const char*)(X + (size_t)(m0 + 192 + rg) * HD) + colb;
  }
  const char* gBa = (const char*)(W1 + (size_t)(n0 + rg) * HD) + colb;
  const char* gBb = (const char*)(W1 + (size_t)(n0 + 64 + rg) * HD) + colb;
  const char* gBc = (const char*)(W3 + (size_t)(n0 + rg) * HD) + colb;
  const char* gBd = (const char*)(W3 + (size_t)(n0 + 64 + rg) * HD) + colb;

#define STG2(P0, O0, P1, O1, KT) { \
    gld16(P0 + (KT) * 128, lds + (O0) + tid * 16); \
    gld16(P1 + (KT) * 128, lds + (O1) + tid * 16); }
#define STG_AQ0(D, KT) STG2(gA0, LDSA(D),         gA2, LDSA(D) + 16384, KT)
#define STG_AQ1(D, KT) STG2(gA1, LDSA(D) + 8192,  gA3, LDSA(D) + 24576, KT)
#define STG_B0(D, KT)  STG2(gBa, LDSB(D),         gBb, LDSB(D) + 8192,  KT)
#define STG_B1(D, KT)  STG2(gBc, LDSB(D) + 16384, gBd, LDSB(D) + 24576, KT)

  bf16x8 a[4][2], b1[2][2], b3[2][2];
  f32x4 acc1[8][2] = {};
  f32x4 acc3[8][2] = {};

#define LD_A(D, IB) \
  _Pragma("unroll") for (int i2 = 0; i2 < 4; i2++) \
  _Pragma("unroll") for (int ks = 0; ks < 2; ks++) \
    a[i2][ks] = *(const bf16x8*)(lds + (D) * 65536 + aoff + ((IB) + i2) * 2048 + ks * 64);
#define LD_B(D, REG, EX) \
  _Pragma("unroll") for (int j = 0; j < 2; j++) \
  _Pragma("unroll") for (int ks = 0; ks < 2; ks++) \
    REG[j][ks] = *(const bf16x8*)(lds + (D) * 65536 + boff + (EX) + j * 2048 + ks * 64);
#define PH_MFMA(ACC, ILO, B) \
  __builtin_amdgcn_s_barrier(); \
  __builtin_amdgcn_s_setprio(1); \
  _Pragma("unroll") for (int i2 = 0; i2 < 4; i2++) \
  _Pragma("unroll") for (int j = 0; j < 2; j++) \
  _Pragma("unroll") for (int ks = 0; ks < 2; ks++) \
    ACC[(ILO) + i2][j] = __builtin_amdgcn_mfma_f32_16x16x32_bf16( \
        a[i2][ks], B[j][ks], ACC[(ILO) + i2][j], 0, 0, 0); \
  __builtin_amdgcn_s_setprio(0); \
  __builtin_amdgcn_s_barrier();

  // prologue: tile0 full (d0), tile1 minus B0 (d1); leaves 3 stages in flight
  STG_AQ0(0, 0); STG_B0(0, 0); STG_B1(0, 0); STG_AQ1(0, 0);
  STG_AQ0(1, 1); STG_B1(1, 1); STG_AQ1(1, 1);
  asm volatile("s_waitcnt vmcnt(6)" ::: "memory");
  __builtin_amdgcn_s_barrier();

#pragma unroll 1
  for (int it = 0; it < 4; ++it) {
    const int t2 = 2 * it + 2, t3 = 2 * it + 3;
    const bool more = it < 3;
    // ---- ph1: reads AQ0d0 + B0d0 (tile 2it)
    LD_A(0, 0); LD_B(0, b1, 0);
    STG_B0(1, 2 * it + 1);
    PH_MFMA(acc1, 0, b1)
    // ---- ph2: reads B1d0
    LD_B(0, b3, 16384);
    if (more) STG_AQ0(0, t2);
    PH_MFMA(acc3, 0, b3)
    // ---- ph3: reads AQ1d0
    LD_A(0, 4);
    if (more) STG_B1(0, t2);
    PH_MFMA(acc3, 4, b3)
    // ---- ph4 (K-tile boundary)
    if (more) STG_AQ1(0, t2);
    if (more) { asm volatile("s_waitcnt vmcnt(6)" ::: "memory"); }
    else      { asm volatile("s_waitcnt vmcnt(0)" ::: "memory"); }
    PH_MFMA(acc1, 4, b1)
    // ---- ph5: reads AQ0d1 + B0d1 (tile 2it+1)
    LD_A(1, 0); LD_B(1, b1, 0);
    if (more) STG_B0(0, t2);
    PH_MFMA(acc1, 0, b1)
    // ---- ph6: reads B1d1
    LD_B(1, b3, 16384);
    if (more) STG_AQ0(1, t3);
    PH_MFMA(acc3, 0, b3)
    // ---- ph7: reads AQ1d1
    LD_A(1, 4);
    if (more) STG_B1(1, t3);
    PH_MFMA(acc3, 4, b3)
    // ---- ph8 (K-tile boundary)
    if (more) STG_AQ1(1, t3);
    if (more) { asm volatile("s_waitcnt vmcnt(6)" ::: "memory"); }
    else      { asm volatile("s_waitcnt vmcnt(0)" ::: "memory"); }
    PH_MFMA(acc1, 4, b1)
  }

  // epilogue: silu(h1)*h3, C/D layout col=lane&15, row=lq*4+r
  int orow0 = m0 + wr * 128;
  int ocol0 = n0 + wc * 32 + lrow;
#pragma unroll
  for (int i = 0; i < 8; i++) {
#pragma unroll
    for (int r = 0; r < 4; r++) {
      int row = orow0 + i * 16 + lq * 4 + r;
      bf16* op = Hout + (size_t)row * N + ocol0;
#pragma unroll
      for (int j = 0; j < 2; j++) {
        float v1 = acc1[i][j][r], v3 = acc3[i][j][r];
        float hv = v1 / (1.f + __expf(-v1)) * v3;
        op[j * 16] = (bf16)hv;
      }
    }
  }
#undef STG2
#undef STG_AQ0
#undef STG_AQ1
#undef STG_B0
#undef STG_B1
#undef LD_A
#undef LD_B
#undef PH_MFMA
}

// ---------------- fused GEMM2: 16x16x32, BM=BN=128, BK=64 (two 32-col halves) --
// Shared tiles FIRST (K=2048, LPT order), routed after. 32KB LDS -> 4 blocks/CU.
__launch_bounds__(256, 4)
__global__ void gemm2_k(const bf16* __restrict__ hmoe, const bf16* __restrict__ hsh,
                        const bf16* __restrict__ e2w, const bf16* __restrict__ s2w,
                        const float* __restrict__ wll, const int* __restrict__ counts,
                        bf16* __restrict__ yslot, bf16* __restrict__ ysh) {
  const bf16 *Hin, *W2;
  const float* wlp = nullptr;
  bf16* Yout;
  int cnt = 0, m0, K;
  bool weighted;
  int y = blockIdx.y;
  if (y < 64) {
    weighted = false;
    Hin = hsh; W2 = s2w; Yout = ysh; K = ISH; m0 = y * 128;
  } else {
    int e = (y - 64) / 20, mt = (y - 64) % 20;
    cnt = min(counts[e], CAP);
    if (mt * 128 >= cnt) return;
    weighted = true;
    Hin = hmoe + (size_t)e * CAP * IM;
    W2 = e2w + (size_t)e * HD * IM;
    wlp = wll + e * CAP;
    Yout = yslot + (size_t)e * CAP * HD;
    K = IM; m0 = mt * 128;
  }
  int n0 = blockIdx.x * 128;

  __shared__ __align__(16) bf16 As[2][128 * 32];
  __shared__ __align__(16) bf16 Bs[2][128 * 32];

  int tid = threadIdx.x;
  int sr = tid >> 2;
  int colb = (tid & 3) * 16;
  const char* apa = (const char*)(Hin + (size_t)(m0 + sr) * K) + colb;
  const char* apb = (const char*)(Hin + (size_t)(m0 + 64 + sr) * K) + colb;
  const char* bpa = (const char*)(W2 + (size_t)(n0 + sr) * K) + colb;
  const char* bpb = (const char*)(W2 + (size_t)(n0 + 64 + sr) * K) + colb;
  char* lA0a = (char*)&As[0][0] + tid * 16;
  char* lA0b = (char*)&As[1][0] + tid * 16;
  char* lA1a = (char*)&As[0][0] + 4096 + tid * 16;
  char* lA1b = (char*)&As[1][0] + 4096 + tid * 16;
  char* lB0a = (char*)&Bs[0][0] + tid * 16;
  char* lB0b = (char*)&Bs[1][0] + tid * 16;
  char* lB1a = (char*)&Bs[0][0] + 4096 + tid * 16;
  char* lB1b = (char*)&Bs[1][0] + 4096 + tid * 16;

  int wid = tid >> 6, lane = tid & 63;
  int wm = (wid >> 1) * 64, wn = (wid & 1) * 64;
  int lrow = lane & 15, lq = lane >> 4;

  f32x4 acc[4][4] = {};

  for (int kb = 0; kb < K * 2; kb += 128) {
    __syncthreads();
    gld16(apa + kb, lA0a);      gld16(apa + kb + 64, lA0b);
    gld16(apb + kb, lA1a);      gld16(apb + kb + 64, lA1b);
    gld16(bpa + kb, lB0a);      gld16(bpa + kb + 64, lB0b);
    gld16(bpb + kb, lB1a);      gld16(bpb + kb + 64, lB1b);
    __syncthreads();
#pragma unroll
    for (int ks = 0; ks < 2; ks++) {
      bf16x8 a[4], b[4];
#pragma unroll
      for (int i = 0; i < 4; i++) {
        a[i] = *(const bf16x8*)&As[ks][(wm + i * 16 + lrow) * 32 + lq * 8];
        b[i] = *(const bf16x8*)&Bs[ks][(wn + i * 16 + lrow) * 32 + lq * 8];
      }
#pragma unroll
      for (int i = 0; i < 4; i++)
#pragma unroll
        for (int j = 0; j < 4; j++)
          acc[i][j] = __builtin_amdgcn_mfma_f32_16x16x32_bf16(a[i], b[j], acc[i][j], 0, 0, 0);
    }
  }

#pragma unroll
  for (int i = 0; i < 4; i++)
#pragma unroll
    for (int r = 0; r < 4; r++) {
      int row = m0 + wm + i * 16 + lq * 4 + r;
      float w = weighted ? ((row < cnt) ? wlp[row] : 0.f) : 1.f;
      bf16* op = Yout + (size_t)row * HD;
#pragma unroll
      for (int j = 0; j < 4; j++)
        op[n0 + wn + j * 16 + lrow] = (bf16)(w * acc[i][j][r]);
    }
}

// ---------------- combine: out[t] = y[pos0] + y[pos1] + sgate*ysh[t] -----------
__launch_bounds__(256)
__global__ void combine_k(const bf16* __restrict__ yslot, const bf16* __restrict__ ysh,
                          const int* __restrict__ pos, const float* __restrict__ sgate,
                          float* __restrict__ out) {
  int wave = threadIdx.x >> 6, lane = threadIdx.x & 63;
  int t = blockIdx.x * 4 + wave;
  int p0 = pos[2 * t], p1 = pos[2 * t + 1];
  float g = sgate[t];
  int col = lane * 8;
  float acc[8];
  {
    const bf16x8 s = *(const bf16x8*)(ysh + (size_t)t * HD + col);
#pragma unroll
    for (int i = 0; i < 8; i++) acc[i] = g * (float)s[i];
  }
  if (p0 >= 0) {
    const bf16x8 v = *(const bf16x8*)(yslot + (size_t)p0 * HD + col);
#pragma unroll
    for (int i = 0; i < 8; i++) acc[i] += (float)v[i];
  }
  if (p1 >= 0) {
    const bf16x8 v = *(const bf16x8*)(yslot + (size_t)p1 * HD + col);
#pragma unroll
    for (int i = 0; i < 8; i++) acc[i] += (float)v[i];
  }
  float* op = out + (size_t)t * HD + col;
#pragma unroll
  for (int i = 0; i < 8; i++) op[i] = acc[i];
}

// ---------------- launch ----------------
extern "C" void kernel_launch(void* const* d_in, const int* in_sizes, int n_in,
                              void* d_out, int out_size, void* d_ws, size_t ws_size,
                              hipStream_t stream) {
  const float* x   = (const float*)d_in[0];
  const float* gw  = (const float*)d_in[1];
  const float* ew1 = (const float*)d_in[2];
  const float* ew2 = (const float*)d_in[3];
  const float* ew3 = (const float*)d_in[4];
  const float* sw1 = (const float*)d_in[5];
  const float* sw2 = (const float*)d_in[6];
  const float* sw3 = (const float*)d_in[7];
  const float* sgw = (const float*)d_in[8];
  float* out = (float*)d_out;
  float* logits = out + (size_t)TOKENS * HD;

  // bf16 staging layout: xb..s3b are dead after gemm1 and are reused as
  // yslot/ysh (29,360,128 B, exact fit); e2b/s2b stay live through gemm2.
  char* w = (char*)d_ws;
  bf16* xb  = (bf16*)w; w += (size_t)TOKENS * HD * 2;
  bf16* e1b = (bf16*)w; w += (size_t)NE * IM * HD * 2;
  bf16* e3b = (bf16*)w; w += (size_t)NE * IM * HD * 2;
  bf16* s1b = (bf16*)w; w += (size_t)ISH * HD * 2;
  bf16* s3b = (bf16*)w; w += (size_t)ISH * HD * 2;
  bf16* e2b = (bf16*)w; w += (size_t)NE * HD * IM * 2;
  bf16* s2b = (bf16*)w; w += (size_t)HD * ISH * 2;
  float* sgate = (float*)w; w += TOKENS * 4;
  int*   topi  = (int*)w;   w += TOKENS * 2 * 4;
  float* topw  = (float*)w; w += TOKENS * 2 * 4;
  int*   counts = (int*)w;  w += 256;
  int*   tok   = (int*)w;   w += NE * CAP * 4;
  float* wl    = (float*)w; w += NE * CAP * 4;
  int*   pos   = (int*)w;   w += TOKENS * 2 * 4;
  bf16* hmoe = (bf16*)w; w += (size_t)NE * CAP * IM * 2;
  bf16* hsh  = (bf16*)w; w += (size_t)TOKENS * ISH * 2;
  bf16* yslot = xb;
  bf16* ysh   = (bf16*)((char*)xb + (size_t)NE * CAP * HD * 2);

  hipLaunchKernelGGL(router_cvt_k, dim3(RT_BLOCKS + CVT_BLOCKS), dim3(256), 0, stream,
                     x, gw, sgw, logits, sgate, topi, topw, counts, xb,
                     ew1, ew3, sw1, sw3, ew2, sw2, e1b);
  hipLaunchKernelGGL(dispatch_k, dim3(TOKENS / 256), dim3(256), 0, stream,
                     topi, topw, counts, tok, wl, pos);
  hipLaunchKernelGGL(gemm1_k, dim3(8, 80 + 64), dim3(512), 0, stream,
                     xb, tok, counts, e1b, e3b, s1b, s3b, hmoe, hsh);
  hipLaunchKernelGGL(gemm2_k, dim3(4, 64 + 160), dim3(256), 0, stream,
                     hmoe, hsh, e2b, s2b, wl, counts, yslot, ysh);
  hipLaunchKernelGGL(combine_k, dim3(TOKENS / 4), dim3(256), 0, stream,
                     yslot, ysh, pos, sgate, out);
}

// Round 2
// 281.847 us; speedup vs baseline: 1.0509x; 1.0509x over previous
//
#include <hip/hip_runtime.h>
#include <hip/hip_bf16.h>
#include <stdint.h>
#include <math.h>

typedef __bf16 bf16;
typedef bf16 bf16x8 __attribute__((ext_vector_type(8)));
typedef bf16 bf16x4 __attribute__((ext_vector_type(4)));
typedef float f32x4 __attribute__((ext_vector_type(4)));
typedef unsigned int u32;

#define TOKENS 8192
#define HD 512
#define NE 8
#define IM 1024
#define ISH 2048
#define CAP 2560   // per-expert slot capacity; mean load 2048, sigma~42

__device__ __forceinline__ void gld16(const void* g, void* l) {
  __builtin_amdgcn_global_load_lds(
      (const __attribute__((address_space(1))) u32*)g,
      (__attribute__((address_space(3))) u32*)l, 16, 0, 0);
}

// ---------------- fused router + weight-convert (one dispatch) ----------------
#define RT_BLOCKS (TOKENS / 4)
#define CVT_BLOCKS 3840
#define CVT_STRIDE (CVT_BLOCKS * 256)   // F4_TOT = 4 * CVT_STRIDE exactly
#define F4_E  (NE * IM * HD / 4)
#define F4_S  (ISH * HD / 4)
#define F4_C1 (F4_E)
#define F4_C2 (F4_C1 + F4_E)
#define F4_C3 (F4_C2 + F4_S)
#define F4_C4 (F4_C3 + F4_S)
#define F4_C5 (F4_C4 + F4_E)
#define F4_TOT (F4_C5 + F4_S)

__launch_bounds__(256)
__global__ void router_cvt_k(const float* __restrict__ x, const float* __restrict__ gw,
                             const float* __restrict__ sgw, float* __restrict__ logits,
                             float* __restrict__ sgate, int* __restrict__ topi,
                             float* __restrict__ topw, int* __restrict__ counts,
                             bf16* __restrict__ xb,
                             const float* __restrict__ e1, const float* __restrict__ e3,
                             const float* __restrict__ s1, const float* __restrict__ s3,
                             const float* __restrict__ e2, const float* __restrict__ s2,
                             bf16* __restrict__ wdst) {
  if (blockIdx.x >= RT_BLOCKS) {
    int idx = (blockIdx.x - RT_BLOCKS) * 256 + threadIdx.x;
#pragma unroll
    for (int it = 0; it < 4; it++, idx += CVT_STRIDE) {
      const float* s; int off;
      if (idx < F4_C1)      { s = e1; off = idx; }
      else if (idx < F4_C2) { s = e3; off = idx - F4_C1; }
      else if (idx < F4_C3) { s = s1; off = idx - F4_C2; }
      else if (idx < F4_C4) { s = s3; off = idx - F4_C3; }
      else if (idx < F4_C5) { s = e2; off = idx - F4_C4; }
      else                  { s = s2; off = idx - F4_C5; }
      const float4 v = ((const float4*)s)[off];
      bf16x4 o;
      o.x = (bf16)v.x; o.y = (bf16)v.y; o.z = (bf16)v.z; o.w = (bf16)v.w;
      ((bf16x4*)wdst)[idx] = o;
    }
    return;
  }
  if (blockIdx.x == 0 && threadIdx.x < NE) counts[threadIdx.x] = 0;
  // gate weights bank-permuted: col c -> (c&7)*64 + c>>3, so gws[e][j*64+lane]
  // is the weight for column lane*8+j (x loaded contiguous-per-lane)
  __shared__ float gws[9][512];
  for (int i = threadIdx.x; i < 9 * 512; i += 256) {
    int r = i >> 9, c = i & 511;
    float v = (r < 8) ? gw[i] : sgw[c];
    gws[r][((c & 7) << 6) | (c >> 3)] = v;
  }
  __syncthreads();
  int wave = threadIdx.x >> 6, lane = threadIdx.x & 63;
  int t = blockIdx.x * 4 + wave;
  const float* xp = x + (size_t)t * HD + lane * 8;
  float4 va = *(const float4*)xp;
  float4 vb = *(const float4*)(xp + 4);
  float xv[8] = {va.x, va.y, va.z, va.w, vb.x, vb.y, vb.z, vb.w};
  {
    bf16x8 xo;
#pragma unroll
    for (int j = 0; j < 8; j++) xo[j] = (bf16)xv[j];
    *(bf16x8*)(xb + (size_t)t * HD + lane * 8) = xo;
  }
  float acc[9];
#pragma unroll
  for (int e = 0; e < 9; e++) {
    float a = 0.f;
#pragma unroll
    for (int j = 0; j < 8; j++) a = fmaf(xv[j], gws[e][j * 64 + lane], a);
    acc[e] = a;
  }
#pragma unroll
  for (int off = 32; off > 0; off >>= 1) {
#pragma unroll
    for (int e = 0; e < 9; e++) acc[e] += __shfl_down(acc[e], off);
  }
  if (lane == 0) {
    float mx = acc[0];
#pragma unroll
    for (int e = 1; e < 8; e++) mx = fmaxf(mx, acc[e]);
    float p[8], sum = 0.f;
#pragma unroll
    for (int e = 0; e < 8; e++) { p[e] = expf(acc[e] - mx); sum += p[e]; }
    float inv = 1.f / sum;
    int i0 = 0; float b0 = p[0];
#pragma unroll
    for (int e = 1; e < 8; e++) if (p[e] > b0) { b0 = p[e]; i0 = e; }
    int i1 = -1; float b1 = -1.f;
#pragma unroll
    for (int e = 0; e < 8; e++) if (e != i0 && p[e] > b1) { b1 = p[e]; i1 = e; }
#pragma unroll
    for (int e = 0; e < 8; e++) logits[(size_t)t * 8 + e] = acc[e];
    topi[2 * t] = i0; topi[2 * t + 1] = i1;
    topw[2 * t] = b0 * inv; topw[2 * t + 1] = b1 * inv;
    sgate[t] = 1.f / (1.f + expf(-acc[8]));
  }
}

// ---------------- dispatch ----------------
__launch_bounds__(256)
__global__ void dispatch_k(const int* __restrict__ topi, const float* __restrict__ topw,
                           int* __restrict__ counts, int* __restrict__ tok,
                           float* __restrict__ wl, int* __restrict__ pos) {
  __shared__ int lcnt[NE];
  __shared__ int lbase[NE];
  int tid = threadIdx.x;
  if (tid < NE) lcnt[tid] = 0;
  __syncthreads();
  int t = blockIdx.x * 256 + tid;
  int e0 = topi[2 * t], e1 = topi[2 * t + 1];
  float w0 = topw[2 * t], w1 = topw[2 * t + 1];
  int r0 = atomicAdd(&lcnt[e0], 1);
  int r1 = atomicAdd(&lcnt[e1], 1);
  __syncthreads();
  if (tid < NE) lbase[tid] = atomicAdd(&counts[tid], lcnt[tid]);
  __syncthreads();
  int p0 = lbase[e0] + r0;
  int p1 = lbase[e1] + r1;
  if (p0 < CAP) { tok[e0 * CAP + p0] = t; wl[e0 * CAP + p0] = w0; }
  if (p1 < CAP) { tok[e1 * CAP + p1] = t; wl[e1 * CAP + p1] = w1; }
  pos[2 * t]     = (p0 < CAP) ? e0 * CAP + p0 : -1;
  pos[2 * t + 1] = (p1 < CAP) ? e1 * CAP + p1 : -1;
}

// ---------------- fused GEMM1 (R6 config: 16x16x32, BM=128 BN=64 dual, BK=64) --
// Best known operating point: ~64 VGPR + 64 AGPR, 32KB LDS, ~3-4 blocks/CU,
// ~91 us. 8-phase/256-tile rewrite (R1 of this session) regressed to 115 us:
// K=512 = 8 K-tiles is too short for the deep pipeline (prologue-dominated,
// 1 block/CU lockstep). Do not re-raise tile without a new occupancy lever.
// XCD swizzle: dispatch order makes XCD = (y*16+x)%8 = x%8, so the 16 x-blocks
// sharing an A-panel span all XCDs -> ~8x A refetch (FETCH 97.5MB vs ~30MB
// unique). Chunked-bijective remap (nwg=4608, q=576) gives each XCD 36
// consecutive y-rows: A-panels and whole-expert W-panels become XCD-local.
__launch_bounds__(256, 4)
__global__ void gemm1_k(const bf16* __restrict__ X, const int* __restrict__ tokl,
                        const int* __restrict__ counts,
                        const bf16* __restrict__ e1w, const bf16* __restrict__ e3w,
                        const bf16* __restrict__ s1w, const bf16* __restrict__ s3w,
                        bf16* __restrict__ hmoe, bf16* __restrict__ hsh) {
  // XCD-chunked bijective swizzle: g in [0,4608), q = 4608/8 = 576
  int g = blockIdx.y * 16 + blockIdx.x;
  int wf = (g & 7) * 576 + (g >> 3);
  int bx = wf & 15, y = wf >> 4;

  const bf16 *W1, *W3;
  bf16* Hout;
  const int* tl = nullptr;
  int cnt = 0, m0, n0, N;
  bool gather;
  if (y < 160) {
    int e = y / 20, mt = y % 20;
    cnt = min(counts[e], CAP);
    if (mt * 128 >= cnt) return;
    gather = true;
    tl = tokl + e * CAP;
    W1 = e1w + (size_t)e * IM * HD;
    W3 = e3w + (size_t)e * IM * HD;
    Hout = hmoe + (size_t)e * CAP * IM;
    N = IM; m0 = mt * 128; n0 = bx * 64;
  } else {
    int s = y - 160;
    gather = false;
    W1 = s1w; W3 = s3w; Hout = hsh; N = ISH;
    m0 = (s >> 1) * 128;
    n0 = ((s & 1) * 16 + bx) * 64;
  }

  __shared__ __align__(16) bf16 As[2][128 * 32];
  __shared__ __align__(16) bf16 B1s[2][64 * 32];
  __shared__ __align__(16) bf16 B3s[2][64 * 32];

  int tid = threadIdx.x;
  int sr = tid >> 2;
  int colb = (tid & 3) * 16;
  int ar0, ar1;
  if (gather) {
    ar0 = tl[min(m0 + sr, cnt - 1)];
    ar1 = tl[min(m0 + 64 + sr, cnt - 1)];
  } else { ar0 = m0 + sr; ar1 = m0 + 64 + sr; }
  const char* apa = (const char*)(X + (size_t)ar0 * HD) + colb;
  const char* apb = (const char*)(X + (size_t)ar1 * HD) + colb;
  const char* bp1 = (const char*)(W1 + (size_t)(n0 + sr) * HD) + colb;
  const char* bp3 = (const char*)(W3 + (size_t)(n0 + sr) * HD) + colb;
  char* lA0a = (char*)&As[0][0] + tid * 16;
  char* lA0b = (char*)&As[1][0] + tid * 16;
  char* lA1a = (char*)&As[0][0] + 4096 + tid * 16;
  char* lA1b = (char*)&As[1][0] + 4096 + tid * 16;
  char* lB1a = (char*)&B1s[0][0] + tid * 16;
  char* lB1b = (char*)&B1s[1][0] + tid * 16;
  char* lB3a = (char*)&B3s[0][0] + tid * 16;
  char* lB3b = (char*)&B3s[1][0] + tid * 16;

  int wid = tid >> 6, lane = tid & 63;
  int wm = (wid >> 1) * 64, wn = (wid & 1) * 32;
  int lrow = lane & 15, lq = lane >> 4;

  f32x4 acc1[4][2] = {};
  f32x4 acc3[4][2] = {};

  for (int kb = 0; kb < 1024; kb += 128) {
    __syncthreads();
    gld16(apa + kb, lA0a);      gld16(apa + kb + 64, lA0b);
    gld16(apb + kb, lA1a);      gld16(apb + kb + 64, lA1b);
    gld16(bp1 + kb, lB1a);      gld16(bp1 + kb + 64, lB1b);
    gld16(bp3 + kb, lB3a);      gld16(bp3 + kb + 64, lB3b);
    __syncthreads();
#pragma unroll
    for (int ks = 0; ks < 2; ks++) {
      bf16x8 a[4], b1[2], b3[2];
#pragma unroll
      for (int i = 0; i < 4; i++)
        a[i] = *(const bf16x8*)&As[ks][(wm + i * 16 + lrow) * 32 + lq * 8];
#pragma unroll
      for (int j = 0; j < 2; j++) {
        b1[j] = *(const bf16x8*)&B1s[ks][(wn + j * 16 + lrow) * 32 + lq * 8];
        b3[j] = *(const bf16x8*)&B3s[ks][(wn + j * 16 + lrow) * 32 + lq * 8];
      }
#pragma unroll
      for (int i = 0; i < 4; i++)
#pragma unroll
        for (int j = 0; j < 2; j++) {
          acc1[i][j] = __builtin_amdgcn_mfma_f32_16x16x32_bf16(a[i], b1[j], acc1[i][j], 0, 0, 0);
          acc3[i][j] = __builtin_amdgcn_mfma_f32_16x16x32_bf16(a[i], b3[j], acc3[i][j], 0, 0, 0);
        }
    }
  }

#pragma unroll
  for (int i = 0; i < 4; i++)
#pragma unroll
    for (int r = 0; r < 4; r++) {
      int row = m0 + wm + i * 16 + lq * 4 + r;
#pragma unroll
      for (int j = 0; j < 2; j++) {
        float v1 = acc1[i][j][r], v3 = acc3[i][j][r];
        float hv = v1 / (1.f + __expf(-v1)) * v3;
        Hout[(size_t)row * N + (n0 + wn + j * 16 + lrow)] = (bf16)hv;
      }
    }
}

// ---------------- fused GEMM2: 16x16x32, BM=BN=128, BK=64 (two 32-col halves) --
// Shared tiles FIRST (K=2048, LPT order), routed after. 32KB LDS -> 4 blocks/CU.
// Same XCD-chunked swizzle (nwg=896, q=112 -> 28 consecutive y per XCD).
__launch_bounds__(256, 4)
__global__ void gemm2_k(const bf16* __restrict__ hmoe, const bf16* __restrict__ hsh,
                        const bf16* __restrict__ e2w, const bf16* __restrict__ s2w,
                        const float* __restrict__ wll, const int* __restrict__ counts,
                        bf16* __restrict__ yslot, bf16* __restrict__ ysh) {
  int g = blockIdx.y * 4 + blockIdx.x;
  int wf = (g & 7) * 112 + (g >> 3);
  int bx = wf & 3, y = wf >> 2;

  const bf16 *Hin, *W2;
  const float* wlp = nullptr;
  bf16* Yout;
  int cnt = 0, m0, K;
  bool weighted;
  if (y < 64) {
    weighted = false;
    Hin = hsh; W2 = s2w; Yout = ysh; K = ISH; m0 = y * 128;
  } else {
    int e = (y - 64) / 20, mt = (y - 64) % 20;
    cnt = min(counts[e], CAP);
    if (mt * 128 >= cnt) return;
    weighted = true;
    Hin = hmoe + (size_t)e * CAP * IM;
    W2 = e2w + (size_t)e * HD * IM;
    wlp = wll + e * CAP;
    Yout = yslot + (size_t)e * CAP * HD;
    K = IM; m0 = mt * 128;
  }
  int n0 = bx * 128;

  __shared__ __align__(16) bf16 As[2][128 * 32];
  __shared__ __align__(16) bf16 Bs[2][128 * 32];

  int tid = threadIdx.x;
  int sr = tid >> 2;
  int colb = (tid & 3) * 16;
  const char* apa = (const char*)(Hin + (size_t)(m0 + sr) * K) + colb;
  const char* apb = (const char*)(Hin + (size_t)(m0 + 64 + sr) * K) + colb;
  const char* bpa = (const char*)(W2 + (size_t)(n0 + sr) * K) + colb;
  const char* bpb = (const char*)(W2 + (size_t)(n0 + 64 + sr) * K) + colb;
  char* lA0a = (char*)&As[0][0] + tid * 16;
  char* lA0b = (char*)&As[1][0] + tid * 16;
  char* lA1a = (char*)&As[0][0] + 4096 + tid * 16;
  char* lA1b = (char*)&As[1][0] + 4096 + tid * 16;
  char* lB0a = (char*)&Bs[0][0] + tid * 16;
  char* lB0b = (char*)&Bs[1][0] + tid * 16;
  char* lB1a = (char*)&Bs[0][0] + 4096 + tid * 16;
  char* lB1b = (char*)&Bs[1][0] + 4096 + tid * 16;

  int wid = tid >> 6, lane = tid & 63;
  int wm = (wid >> 1) * 64, wn = (wid & 1) * 64;
  int lrow = lane & 15, lq = lane >> 4;

  f32x4 acc[4][4] = {};

  for (int kb = 0; kb < K * 2; kb += 128) {
    __syncthreads();
    gld16(apa + kb, lA0a);      gld16(apa + kb + 64, lA0b);
    gld16(apb + kb, lA1a);      gld16(apb + kb + 64, lA1b);
    gld16(bpa + kb, lB0a);      gld16(bpa + kb + 64, lB0b);
    gld16(bpb + kb, lB1a);      gld16(bpb + kb + 64, lB1b);
    __syncthreads();
#pragma unroll
    for (int ks = 0; ks < 2; ks++) {
      bf16x8 a[4], b[4];
#pragma unroll
      for (int i = 0; i < 4; i++) {
        a[i] = *(const bf16x8*)&As[ks][(wm + i * 16 + lrow) * 32 + lq * 8];
        b[i] = *(const bf16x8*)&Bs[ks][(wn + i * 16 + lrow) * 32 + lq * 8];
      }
#pragma unroll
      for (int i = 0; i < 4; i++)
#pragma unroll
        for (int j = 0; j < 4; j++)
          acc[i][j] = __builtin_amdgcn_mfma_f32_16x16x32_bf16(a[i], b[j], acc[i][j], 0, 0, 0);
    }
  }

#pragma unroll
  for (int i = 0; i < 4; i++)
#pragma unroll
    for (int r = 0; r < 4; r++) {
      int row = m0 + wm + i * 16 + lq * 4 + r;
      float w = weighted ? ((row < cnt) ? wlp[row] : 0.f) : 1.f;
      bf16* op = Yout + (size_t)row * HD;
#pragma unroll
      for (int j = 0; j < 4; j++)
        op[n0 + wn + j * 16 + lrow] = (bf16)(w * acc[i][j][r]);
    }
}

// ---------------- combine: out[t] = y[pos0] + y[pos1] + sgate*ysh[t] -----------
__launch_bounds__(256)
__global__ void combine_k(const bf16* __restrict__ yslot, const bf16* __restrict__ ysh,
                          const int* __restrict__ pos, const float* __restrict__ sgate,
                          float* __restrict__ out) {
  int wave = threadIdx.x >> 6, lane = threadIdx.x & 63;
  int t = blockIdx.x * 4 + wave;
  int p0 = pos[2 * t], p1 = pos[2 * t + 1];
  float g = sgate[t];
  int col = lane * 8;
  float acc[8];
  {
    const bf16x8 s = *(const bf16x8*)(ysh + (size_t)t * HD + col);
#pragma unroll
    for (int i = 0; i < 8; i++) acc[i] = g * (float)s[i];
  }
  if (p0 >= 0) {
    const bf16x8 v = *(const bf16x8*)(yslot + (size_t)p0 * HD + col);
#pragma unroll
    for (int i = 0; i < 8; i++) acc[i] += (float)v[i];
  }
  if (p1 >= 0) {
    const bf16x8 v = *(const bf16x8*)(yslot + (size_t)p1 * HD + col);
#pragma unroll
    for (int i = 0; i < 8; i++) acc[i] += (float)v[i];
  }
  float* op = out + (size_t)t * HD + col;
#pragma unroll
  for (int i = 0; i < 8; i++) op[i] = acc[i];
}

// ---------------- launch ----------------
extern "C" void kernel_launch(void* const* d_in, const int* in_sizes, int n_in,
                              void* d_out, int out_size, void* d_ws, size_t ws_size,
                              hipStream_t stream) {
  const float* x   = (const float*)d_in[0];
  const float* gw  = (const float*)d_in[1];
  const float* ew1 = (const float*)d_in[2];
  const float* ew2 = (const float*)d_in[3];
  const float* ew3 = (const float*)d_in[4];
  const float* sw1 = (const float*)d_in[5];
  const float* sw2 = (const float*)d_in[6];
  const float* sw3 = (const float*)d_in[7];
  const float* sgw = (const float*)d_in[8];
  float* out = (float*)d_out;
  float* logits = out + (size_t)TOKENS * HD;

  // bf16 staging layout: xb..s3b are dead after gemm1 and are reused as
  // yslot/ysh (29,360,128 B, exact fit); e2b/s2b stay live through gemm2.
  char* w = (char*)d_ws;
  bf16* xb  = (bf16*)w; w += (size_t)TOKENS * HD * 2;
  bf16* e1b = (bf16*)w; w += (size_t)NE * IM * HD * 2;
  bf16* e3b = (bf16*)w; w += (size_t)NE * IM * HD * 2;
  bf16* s1b = (bf16*)w; w += (size_t)ISH * HD * 2;
  bf16* s3b = (bf16*)w; w += (size_t)ISH * HD * 2;
  bf16* e2b = (bf16*)w; w += (size_t)NE * HD * IM * 2;
  bf16* s2b = (bf16*)w; w += (size_t)HD * ISH * 2;
  float* sgate = (float*)w; w += TOKENS * 4;
  int*   topi  = (int*)w;   w += TOKENS * 2 * 4;
  float* topw  = (float*)w; w += TOKENS * 2 * 4;
  int*   counts = (int*)w;  w += 256;
  int*   tok   = (int*)w;   w += NE * CAP * 4;
  float* wl    = (float*)w; w += NE * CAP * 4;
  int*   pos   = (int*)w;   w += TOKENS * 2 * 4;
  bf16* hmoe = (bf16*)w; w += (size_t)NE * CAP * IM * 2;
  bf16* hsh  = (bf16*)w; w += (size_t)TOKENS * ISH * 2;
  bf16* yslot = xb;
  bf16* ysh   = (bf16*)((char*)xb + (size_t)NE * CAP * HD * 2);

  hipLaunchKernelGGL(router_cvt_k, dim3(RT_BLOCKS + CVT_BLOCKS), dim3(256), 0, stream,
                     x, gw, sgw, logits, sgate, topi, topw, counts, xb,
                     ew1, ew3, sw1, sw3, ew2, sw2, e1b);
  hipLaunchKernelGGL(dispatch_k, dim3(TOKENS / 256), dim3(256), 0, stream,
                     topi, topw, counts, tok, wl, pos);
  hipLaunchKernelGGL(gemm1_k, dim3(16, 160 + 128), dim3(256), 0, stream,
                     xb, tok, counts, e1b, e3b, s1b, s3b, hmoe, hsh);
  hipLaunchKernelGGL(gemm2_k, dim3(4, 64 + 160), dim3(256), 0, stream,
                     hmoe, hsh, e2b, s2b, wl, counts, yslot, ysh);
  hipLaunchKernelGGL(combine_k, dim3(TOKENS / 4), dim3(256), 0, stream,
                     yslot, ysh, pos, sgate, out);
}

// Round 4
// 264.996 us; speedup vs baseline: 1.1178x; 1.0636x over previous
//
#include <hip/hip_runtime.h>
#include <hip/hip_bf16.h>
#include <stdint.h>
#include <math.h>

typedef __bf16 bf16;
typedef bf16 bf16x8 __attribute__((ext_vector_type(8)));
typedef bf16 bf16x4 __attribute__((ext_vector_type(4)));
typedef float f32x4 __attribute__((ext_vector_type(4)));
typedef unsigned int u32;

#define TOKENS 8192
#define HD 512
#define NE 8
#define IM 1024
#define ISH 2048
#define CAP 2560   // per-expert slot capacity; mean load 2048, sigma~42

__device__ __forceinline__ void gld16(const void* g, void* l) {
  __builtin_amdgcn_global_load_lds(
      (const __attribute__((address_space(1))) u32*)g,
      (__attribute__((address_space(3))) u32*)l, 16, 0, 0);
}

// ---------------- fused router + weight-convert (one dispatch) ----------------
#define RT_BLOCKS (TOKENS / 4)
#define CVT_BLOCKS 3840
#define CVT_STRIDE (CVT_BLOCKS * 256)   // F4_TOT = 4 * CVT_STRIDE exactly
#define F4_E  (NE * IM * HD / 4)
#define F4_S  (ISH * HD / 4)
#define F4_C1 (F4_E)
#define F4_C2 (F4_C1 + F4_E)
#define F4_C3 (F4_C2 + F4_S)
#define F4_C4 (F4_C3 + F4_S)
#define F4_C5 (F4_C4 + F4_E)
#define F4_TOT (F4_C5 + F4_S)

__launch_bounds__(256)
__global__ void router_cvt_k(const float* __restrict__ x, const float* __restrict__ gw,
                             const float* __restrict__ sgw, float* __restrict__ logits,
                             float* __restrict__ sgate, int* __restrict__ topi,
                             float* __restrict__ topw, int* __restrict__ counts,
                             bf16* __restrict__ xb,
                             const float* __restrict__ e1, const float* __restrict__ e3,
                             const float* __restrict__ s1, const float* __restrict__ s3,
                             const float* __restrict__ e2, const float* __restrict__ s2,
                             bf16* __restrict__ wdst) {
  if (blockIdx.x >= RT_BLOCKS) {
    int idx = (blockIdx.x - RT_BLOCKS) * 256 + threadIdx.x;
#pragma unroll
    for (int it = 0; it < 4; it++, idx += CVT_STRIDE) {
      const float* s; int off;
      if (idx < F4_C1)      { s = e1; off = idx; }
      else if (idx < F4_C2) { s = e3; off = idx - F4_C1; }
      else if (idx < F4_C3) { s = s1; off = idx - F4_C2; }
      else if (idx < F4_C4) { s = s3; off = idx - F4_C3; }
      else if (idx < F4_C5) { s = e2; off = idx - F4_C4; }
      else                  { s = s2; off = idx - F4_C5; }
      const float4 v = ((const float4*)s)[off];
      bf16x4 o;
      o.x = (bf16)v.x; o.y = (bf16)v.y; o.z = (bf16)v.z; o.w = (bf16)v.w;
      ((bf16x4*)wdst)[idx] = o;
    }
    return;
  }
  if (blockIdx.x == 0 && threadIdx.x < NE) counts[threadIdx.x] = 0;
  // gate weights bank-permuted: col c -> (c&7)*64 + c>>3, so gws[e][j*64+lane]
  // is the weight for column lane*8+j (x loaded contiguous-per-lane)
  __shared__ float gws[9][512];
  for (int i = threadIdx.x; i < 9 * 512; i += 256) {
    int r = i >> 9, c = i & 511;
    float v = (r < 8) ? gw[i] : sgw[c];
    gws[r][((c & 7) << 6) | (c >> 3)] = v;
  }
  __syncthreads();
  int wave = threadIdx.x >> 6, lane = threadIdx.x & 63;
  int t = blockIdx.x * 4 + wave;
  const float* xp = x + (size_t)t * HD + lane * 8;
  float4 va = *(const float4*)xp;
  float4 vb = *(const float4*)(xp + 4);
  float xv[8] = {va.x, va.y, va.z, va.w, vb.x, vb.y, vb.z, vb.w};
  {
    bf16x8 xo;
#pragma unroll
    for (int j = 0; j < 8; j++) xo[j] = (bf16)xv[j];
    *(bf16x8*)(xb + (size_t)t * HD + lane * 8) = xo;
  }
  float acc[9];
#pragma unroll
  for (int e = 0; e < 9; e++) {
    float a = 0.f;
#pragma unroll
    for (int j = 0; j < 8; j++) a = fmaf(xv[j], gws[e][j * 64 + lane], a);
    acc[e] = a;
  }
#pragma unroll
  for (int off = 32; off > 0; off >>= 1) {
#pragma unroll
    for (int e = 0; e < 9; e++) acc[e] += __shfl_down(acc[e], off);
  }
  if (lane == 0) {
    float mx = acc[0];
#pragma unroll
    for (int e = 1; e < 8; e++) mx = fmaxf(mx, acc[e]);
    float p[8], sum = 0.f;
#pragma unroll
    for (int e = 0; e < 8; e++) { p[e] = expf(acc[e] - mx); sum += p[e]; }
    float inv = 1.f / sum;
    int i0 = 0; float b0 = p[0];
#pragma unroll
    for (int e = 1; e < 8; e++) if (p[e] > b0) { b0 = p[e]; i0 = e; }
    int i1 = -1; float b1 = -1.f;
#pragma unroll
    for (int e = 0; e < 8; e++) if (e != i0 && p[e] > b1) { b1 = p[e]; i1 = e; }
#pragma unroll
    for (int e = 0; e < 8; e++) logits[(size_t)t * 8 + e] = acc[e];
    topi[2 * t] = i0; topi[2 * t + 1] = i1;
    topw[2 * t] = b0 * inv; topw[2 * t + 1] = b1 * inv;
    sgate[t] = 1.f / (1.f + expf(-acc[8]));
  }
}

// ---------------- dispatch ----------------
__launch_bounds__(256)
__global__ void dispatch_k(const int* __restrict__ topi, const float* __restrict__ topw,
                           int* __restrict__ counts, int* __restrict__ tok,
                           float* __restrict__ wl, int* __restrict__ pos) {
  __shared__ int lcnt[NE];
  __shared__ int lbase[NE];
  int tid = threadIdx.x;
  if (tid < NE) lcnt[tid] = 0;
  __syncthreads();
  int t = blockIdx.x * 256 + tid;
  int e0 = topi[2 * t], e1 = topi[2 * t + 1];
  float w0 = topw[2 * t], w1 = topw[2 * t + 1];
  int r0 = atomicAdd(&lcnt[e0], 1);
  int r1 = atomicAdd(&lcnt[e1], 1);
  __syncthreads();
  if (tid < NE) lbase[tid] = atomicAdd(&counts[tid], lcnt[tid]);
  __syncthreads();
  int p0 = lbase[e0] + r0;
  int p1 = lbase[e1] + r1;
  if (p0 < CAP) { tok[e0 * CAP + p0] = t; wl[e0 * CAP + p0] = w0; }
  if (p1 < CAP) { tok[e1 * CAP + p1] = t; wl[e1 * CAP + p1] = w1; }
  pos[2 * t]     = (p0 < CAP) ? e0 * CAP + p0 : -1;
  pos[2 * t + 1] = (p1 < CAP) ? e1 * CAP + p1 : -1;
}

// ---------------- fused GEMM1 (R6 config: 16x16x32, BM=128 BN=64 dual, BK=64) --
// Best known operating point: ~64 VGPR + 64 AGPR, 32KB LDS, 4 blocks/CU, ~87us.
// 8-phase/256-tile rewrite regressed (K=512 too short); chunked XCD swizzle
// (R2) cut FETCH 97->75MB and 4.4us but left a ~20% shared-vs-routed XCD
// imbalance. This round: expert-aligned balanced map — XCD j gets expert j's
// 20 mt-tiles (16 active) + 16 shared y-rows = 512 active blocks per XCD, and
// expert j's W1/W3 + token panels become XCD-private (W fetched ~once).
__launch_bounds__(256, 4)
__global__ void gemm1_k(const bf16* __restrict__ X, const int* __restrict__ tokl,
                        const int* __restrict__ counts,
                        const bf16* __restrict__ e1w, const bf16* __restrict__ e3w,
                        const bf16* __restrict__ s1w, const bf16* __restrict__ s3w,
                        bf16* __restrict__ hmoe, bf16* __restrict__ hsh) {
  // balanced expert-aligned XCD map (XCD = g%8 model confirmed by R2 FETCH):
  // XCD j: i<320 -> expert j routed (y = 20j + i/16), else shared (y = 160+16j+...)
  int g = blockIdx.y * 16 + blockIdx.x;
  int xcd = g & 7, i = g >> 3;
  int y, bx;
  if (i < 320) { y = xcd * 20 + (i >> 4); bx = i & 15; }
  else { int s = i - 320; y = 160 + xcd * 16 + (s >> 4); bx = s & 15; }

  const bf16 *W1, *W3;
  bf16* Hout;
  const int* tl = nullptr;
  int cnt = 0, m0, n0, N;
  bool gather;
  if (y < 160) {
    int e = y / 20, mt = y % 20;
    cnt = min(counts[e], CAP);
    if (mt * 128 >= cnt) return;
    gather = true;
    tl = tokl + e * CAP;
    W1 = e1w + (size_t)e * IM * HD;
    W3 = e3w + (size_t)e * IM * HD;
    Hout = hmoe + (size_t)e * CAP * IM;
    N = IM; m0 = mt * 128; n0 = bx * 64;
  } else {
    int s = y - 160;
    gather = false;
    W1 = s1w; W3 = s3w; Hout = hsh; N = ISH;
    m0 = (s >> 1) * 128;
    n0 = ((s & 1) * 16 + bx) * 64;
  }

  __shared__ __align__(16) bf16 As[2][128 * 32];
  __shared__ __align__(16) bf16 B1s[2][64 * 32];
  __shared__ __align__(16) bf16 B3s[2][64 * 32];

  int tid = threadIdx.x;
  int sr = tid >> 2;
  int colb = (tid & 3) * 16;
  int ar0, ar1;
  if (gather) {
    ar0 = tl[min(m0 + sr, cnt - 1)];
    ar1 = tl[min(m0 + 64 + sr, cnt - 1)];
  } else { ar0 = m0 + sr; ar1 = m0 + 64 + sr; }
  const char* apa = (const char*)(X + (size_t)ar0 * HD) + colb;
  const char* apb = (const char*)(X + (size_t)ar1 * HD) + colb;
  const char* bp1 = (const char*)(W1 + (size_t)(n0 + sr) * HD) + colb;
  const char* bp3 = (const char*)(W3 + (size_t)(n0 + sr) * HD) + colb;
  char* lA0a = (char*)&As[0][0] + tid * 16;
  char* lA0b = (char*)&As[1][0] + tid * 16;
  char* lA1a = (char*)&As[0][0] + 4096 + tid * 16;
  char* lA1b = (char*)&As[1][0] + 4096 + tid * 16;
  char* lB1a = (char*)&B1s[0][0] + tid * 16;
  char* lB1b = (char*)&B1s[1][0] + tid * 16;
  char* lB3a = (char*)&B3s[0][0] + tid * 16;
  char* lB3b = (char*)&B3s[1][0] + tid * 16;

  int wid = tid >> 6, lane = tid & 63;
  int wm = (wid >> 1) * 64, wn = (wid & 1) * 32;
  int lrow = lane & 15, lq = lane >> 4;

  f32x4 acc1[4][2] = {};
  f32x4 acc3[4][2] = {};

  for (int kb = 0; kb < 1024; kb += 128) {
    __syncthreads();
    gld16(apa + kb, lA0a);      gld16(apa + kb + 64, lA0b);
    gld16(apb + kb, lA1a);      gld16(apb + kb + 64, lA1b);
    gld16(bp1 + kb, lB1a);      gld16(bp1 + kb + 64, lB1b);
    gld16(bp3 + kb, lB3a);      gld16(bp3 + kb + 64, lB3b);
    __syncthreads();
#pragma unroll
    for (int ks = 0; ks < 2; ks++) {
      bf16x8 a[4], b1[2], b3[2];
#pragma unroll
      for (int i2 = 0; i2 < 4; i2++)
        a[i2] = *(const bf16x8*)&As[ks][(wm + i2 * 16 + lrow) * 32 + lq * 8];
#pragma unroll
      for (int j = 0; j < 2; j++) {
        b1[j] = *(const bf16x8*)&B1s[ks][(wn + j * 16 + lrow) * 32 + lq * 8];
        b3[j] = *(const bf16x8*)&B3s[ks][(wn + j * 16 + lrow) * 32 + lq * 8];
      }
#pragma unroll
      for (int i2 = 0; i2 < 4; i2++)
#pragma unroll
        for (int j = 0; j < 2; j++) {
          acc1[i2][j] = __builtin_amdgcn_mfma_f32_16x16x32_bf16(a[i2], b1[j], acc1[i2][j], 0, 0, 0);
          acc3[i2][j] = __builtin_amdgcn_mfma_f32_16x16x32_bf16(a[i2], b3[j], acc3[i2][j], 0, 0, 0);
        }
    }
  }

#pragma unroll
  for (int i2 = 0; i2 < 4; i2++)
#pragma unroll
    for (int r = 0; r < 4; r++) {
      int row = m0 + wm + i2 * 16 + lq * 4 + r;
#pragma unroll
      for (int j = 0; j < 2; j++) {
        float v1 = acc1[i2][j][r], v3 = acc3[i2][j][r];
        float hv = v1 / (1.f + __expf(-v1)) * v3;
        Hout[(size_t)row * N + (n0 + wn + j * 16 + lrow)] = (bf16)hv;
      }
    }
}

// ---------------- fused GEMM2: 16x16x32, BM=BN=128, BK=64 (two 32-col halves) --
// 32KB LDS -> 4 blocks/CU. Balanced expert-aligned XCD map: XCD j gets 8
// shared y (K=2048, issued first) + expert j's 20 mt-tiles (K=1024, 16
// active) = 128 work-units per XCD, W2/hmoe panels XCD-local. R2's chunked
// map was XCD-imbalanced (2.5x) and regressed the total — do not chunk
// heterogeneous work classes.
__launch_bounds__(256, 4)
__global__ void gemm2_k(const bf16* __restrict__ hmoe, const bf16* __restrict__ hsh,
                        const bf16* __restrict__ e2w, const bf16* __restrict__ s2w,
                        const float* __restrict__ wll, const int* __restrict__ counts,
                        bf16* __restrict__ yslot, bf16* __restrict__ ysh) {
  int g = blockIdx.y * 4 + blockIdx.x;
  int xcd = g & 7, i = g >> 3;
  int y, bx;
  if (i < 32) { y = xcd * 8 + (i >> 2); bx = i & 3; }
  else { int r = i - 32; y = 64 + xcd * 20 + (r >> 2); bx = r & 3; }

  const bf16 *Hin, *W2;
  const float* wlp = nullptr;
  bf16* Yout;
  int cnt = 0, m0, K;
  bool weighted;
  if (y < 64) {
    weighted = false;
    Hin = hsh; W2 = s2w; Yout = ysh; K = ISH; m0 = y * 128;
  } else {
    int e = (y - 64) / 20, mt = (y - 64) % 20;
    cnt = min(counts[e], CAP);
    if (mt * 128 >= cnt) return;
    weighted = true;
    Hin = hmoe + (size_t)e * CAP * IM;
    W2 = e2w + (size_t)e * HD * IM;
    wlp = wll + e * CAP;
    Yout = yslot + (size_t)e * CAP * HD;
    K = IM; m0 = mt * 128;
  }
  int n0 = bx * 128;

  __shared__ __align__(16) bf16 As[2][128 * 32];
  __shared__ __align__(16) bf16 Bs[2][128 * 32];

  int tid = threadIdx.x;
  int sr = tid >> 2;
  int colb = (tid & 3) * 16;
  const char* apa = (const char*)(Hin + (size_t)(m0 + sr) * K) + colb;
  const char* apb = (const char*)(Hin + (size_t)(m0 + 64 + sr) * K) + colb;
  const char* bpa = (const char*)(W2 + (size_t)(n0 + sr) * K) + colb;
  const char* bpb = (const char*)(W2 + (size_t)(n0 + 64 + sr) * K) + colb;
  char* lA0a = (char*)&As[0][0] + tid * 16;
  char* lA0b = (char*)&As[1][0] + tid * 16;
  char* lA1a = (char*)&As[0][0] + 4096 + tid * 16;
  char* lA1b = (char*)&As[1][0] + 4096 + tid * 16;
  char* lB0a = (char*)&Bs[0][0] + tid * 16;
  char* lB0b = (char*)&Bs[1][0] + tid * 16;
  char* lB1a = (char*)&Bs[0][0] + 4096 + tid * 16;
  char* lB1b = (char*)&Bs[1][0] + 4096 + tid * 16;

  int wid = tid >> 6, lane = tid & 63;
  int wm = (wid >> 1) * 64, wn = (wid & 1) * 64;
  int lrow = lane & 15, lq = lane >> 4;

  f32x4 acc[4][4] = {};

  for (int kb = 0; kb < K * 2; kb += 128) {
    __syncthreads();
    gld16(apa + kb, lA0a);      gld16(apa + kb + 64, lA0b);
    gld16(apb + kb, lA1a);      gld16(apb + kb + 64, lA1b);
    gld16(bpa + kb, lB0a);      gld16(bpa + kb + 64, lB0b);
    gld16(bpb + kb, lB1a);      gld16(bpb + kb + 64, lB1b);
    __syncthreads();
#pragma unroll
    for (int ks = 0; ks < 2; ks++) {
      bf16x8 a[4], b[4];
#pragma unroll
      for (int i2 = 0; i2 < 4; i2++) {
        a[i2] = *(const bf16x8*)&As[ks][(wm + i2 * 16 + lrow) * 32 + lq * 8];
        b[i2] = *(const bf16x8*)&Bs[ks][(wn + i2 * 16 + lrow) * 32 + lq * 8];
      }
#pragma unroll
      for (int i2 = 0; i2 < 4; i2++)
#pragma unroll
        for (int j = 0; j < 4; j++)
          acc[i2][j] = __builtin_amdgcn_mfma_f32_16x16x32_bf16(a[i2], b[j], acc[i2][j], 0, 0, 0);
    }
  }

#pragma unroll
  for (int i2 = 0; i2 < 4; i2++)
#pragma unroll
    for (int r = 0; r < 4; r++) {
      int row = m0 + wm + i2 * 16 + lq * 4 + r;
      float w = weighted ? ((row < cnt) ? wlp[row] : 0.f) : 1.f;
      bf16* op = Yout + (size_t)row * HD;
#pragma unroll
      for (int j = 0; j < 4; j++)
        op[n0 + wn + j * 16 + lrow] = (bf16)(w * acc[i2][j][r]);
    }
}

// ---------------- combine: out[t] = y[pos0] + y[pos1] + sgate*ysh[t] -----------
__launch_bounds__(256)
__global__ void combine_k(const bf16* __restrict__ yslot, const bf16* __restrict__ ysh,
                          const int* __restrict__ pos, const float* __restrict__ sgate,
                          float* __restrict__ out) {
  int wave = threadIdx.x >> 6, lane = threadIdx.x & 63;
  int t = blockIdx.x * 4 + wave;
  int p0 = pos[2 * t], p1 = pos[2 * t + 1];
  float g = sgate[t];
  int col = lane * 8;
  float acc[8];
  {
    const bf16x8 s = *(const bf16x8*)(ysh + (size_t)t * HD + col);
#pragma unroll
    for (int i = 0; i < 8; i++) acc[i] = g * (float)s[i];
  }
  if (p0 >= 0) {
    const bf16x8 v = *(const bf16x8*)(yslot + (size_t)p0 * HD + col);
#pragma unroll
    for (int i = 0; i < 8; i++) acc[i] += (float)v[i];
  }
  if (p1 >= 0) {
    const bf16x8 v = *(const bf16x8*)(yslot + (size_t)p1 * HD + col);
#pragma unroll
    for (int i = 0; i < 8; i++) acc[i] += (float)v[i];
  }
  float* op = out + (size_t)t * HD + col;
#pragma unroll
  for (int i = 0; i < 8; i++) op[i] = acc[i];
}

// ---------------- launch ----------------
extern "C" void kernel_launch(void* const* d_in, const int* in_sizes, int n_in,
                              void* d_out, int out_size, void* d_ws, size_t ws_size,
                              hipStream_t stream) {
  const float* x   = (const float*)d_in[0];
  const float* gw  = (const float*)d_in[1];
  const float* ew1 = (const float*)d_in[2];
  const float* ew2 = (const float*)d_in[3];
  const float* ew3 = (const float*)d_in[4];
  const float* sw1 = (const float*)d_in[5];
  const float* sw2 = (const float*)d_in[6];
  const float* sw3 = (const float*)d_in[7];
  const float* sgw = (const float*)d_in[8];
  float* out = (float*)d_out;
  float* logits = out + (size_t)TOKENS * HD;

  // bf16 staging layout: xb..s3b are dead after gemm1 and are reused as
  // yslot/ysh (29,360,128 B, exact fit); e2b/s2b stay live through gemm2.
  char* w = (char*)d_ws;
  bf16* xb  = (bf16*)w; w += (size_t)TOKENS * HD * 2;
  bf16* e1b = (bf16*)w; w += (size_t)NE * IM * HD * 2;
  bf16* e3b = (bf16*)w; w += (size_t)NE * IM * HD * 2;
  bf16* s1b = (bf16*)w; w += (size_t)ISH * HD * 2;
  bf16* s3b = (bf16*)w; w += (size_t)ISH * HD * 2;
  bf16* e2b = (bf16*)w; w += (size_t)NE * HD * IM * 2;
  bf16* s2b = (bf16*)w; w += (size_t)HD * ISH * 2;
  float* sgate = (float*)w; w += TOKENS * 4;
  int*   topi  = (int*)w;   w += TOKENS * 2 * 4;
  float* topw  = (float*)w; w += TOKENS * 2 * 4;
  int*   counts = (int*)w;  w += 256;
  int*   tok   = (int*)w;   w += NE * CAP * 4;
  float* wl    = (float*)w; w += NE * CAP * 4;
  int*   pos   = (int*)w;   w += TOKENS * 2 * 4;
  bf16* hmoe = (bf16*)w; w += (size_t)NE * CAP * IM * 2;
  bf16* hsh  = (bf16*)w; w += (size_t)TOKENS * ISH * 2;
  bf16* yslot = xb;
  bf16* ysh   = (bf16*)((char*)xb + (size_t)NE * CAP * HD * 2);

  hipLaunchKernelGGL(router_cvt_k, dim3(RT_BLOCKS + CVT_BLOCKS), dim3(256), 0, stream,
                     x, gw, sgw, logits, sgate, topi, topw, counts, xb,
                     ew1, ew3, sw1, sw3, ew2, sw2, e1b);
  hipLaunchKernelGGL(dispatch_k, dim3(TOKENS / 256), dim3(256), 0, stream,
                     topi, topw, counts, tok, wl, pos);
  hipLaunchKernelGGL(gemm1_k, dim3(16, 160 + 128), dim3(256), 0, stream,
                     xb, tok, counts, e1b, e3b, s1b, s3b, hmoe, hsh);
  hipLaunchKernelGGL(gemm2_k, dim3(4, 64 + 160), dim3(256), 0, stream,
                     hmoe, hsh, e2b, s2b, wl, counts, yslot, ysh);
  hipLaunchKernelGGL(combine_k, dim3(TOKENS / 4), dim3(256), 0, stream,
                     yslot, ysh, pos, sgate, out);
}